// Round 2
// baseline (5194.404 us; speedup 1.0000x reference)
//
#include <hip/hip_runtime.h>
#include <hip/hip_cooperative_groups.h>

namespace cg = cooperative_groups;

// Problem constants (from reference)
constexpr int B_ = 16, T_ = 128, S_ = 128;
constexpr int ROWS = B_ * S_;        // 2048
constexpr int NSTEPS = T_ - 1;       // 127
constexpr int TPRED = 20;
constexpr int TOUT = NSTEPS - TPRED; // 107
constexpr int RPB = 16;              // rows per row-tile (MFMA M)
constexpr int TB = 512;              // 8 waves
constexpr int NBLK = 256;            // 128 A-role + 128 B-role blocks

// ws layout in 4-byte units.
constexpr int OFF_HN = 0;                       // [2][2048][64] f16 (parity = step&1)
constexpr int OFF_HS = OFF_HN + 131072;
constexpr int OFF_HD = OFF_HS + 131072;         // [2][2048][128] f16
constexpr int OFF_CN = OFF_HD + 262144;         // (c-state now in registers; region unused)
constexpr int OFF_CS = OFF_CN + 131072;
constexpr int OFF_CD = OFF_CS + 131072;
constexpr int OFF_GP = OFF_CD + 262144;         // gpart[2][128][8][4][64][4] f32
constexpr int OFF_OUTS = OFF_GP + 2097152;      // outs[127][2048][2] f32
constexpr int ZERO_DW = OFF_CN;                 // zero h buffers only (c is in regs)
// packed fp16 weight fragments
constexpr int OFF_NPK = OFF_OUTS + NSTEPS * ROWS * 2;
constexpr int NPK_DW = 16 * 7 * 256;            // 28672
constexpr int OFF_SPK = OFF_NPK + NPK_DW;
constexpr int OFF_DPK = OFF_SPK + NPK_DW;       // 32 nt * 16 tiles * 256 dw
constexpr int DPK_DW = 32 * 16 * 256;           // 131072
constexpr int PACK_DWORDS = 2 * NPK_DW + DPK_DW;

typedef _Float16 half8 __attribute__((ext_vector_type(8)));
typedef float float4v __attribute__((ext_vector_type(4)));

__device__ __forceinline__ float sigm(float x) { return 1.f / (1.f + __expf(-x)); }
__device__ __forceinline__ float tanh_(float x) { return 2.f / (1.f + __expf(-2.f * x)) - 1.f; }
__device__ __forceinline__ unsigned int pack2(float a, float b) {
    union { unsigned int u; _Float16 h[2]; } x;
    x.h[0] = (_Float16)a; x.h[1] = (_Float16)b; return x.u;
}

// ---- pack fp32 weights into MFMA B-fragment tiles (fp16), once per call ----
// B-frag 16x16x32: lane l holds B[k=(l>>4)*8+j][n=l&15] -> tile = 512 f16 = 256 dw.
// n/s packs per nt(16): [Wh kt0, Wh kt1, Wa kt0, Wa kt1, Wb kt0, Wb kt1, Xaug]
// d pack per nt(32): [dWx kt0..3, dWh kt0..3, dWa kt0..3, dWb kt0..3]
__global__ __launch_bounds__(256) void pack_weights(
    const float* __restrict__ nWx, const float* __restrict__ nWh,
    const float* __restrict__ nWa, const float* __restrict__ nWb, const float* __restrict__ nb,
    const float* __restrict__ sWx, const float* __restrict__ sWh,
    const float* __restrict__ sWa, const float* __restrict__ sWb, const float* __restrict__ sb,
    const float* __restrict__ dWx, const float* __restrict__ dWh,
    const float* __restrict__ dWa, const float* __restrict__ dWb,
    unsigned int* __restrict__ wsu)
{
    int idx = blockIdx.x * 256 + threadIdx.x;
    if (idx >= PACK_DWORDS) return;
    if (idx < 2 * NPK_DW) {
        bool isS = idx >= NPK_DW;
        int dn = isS ? idx - NPK_DW : idx;
        int tile = dn >> 8;
        int e = (dn & 255) * 2;
        int lane = e >> 3, j0 = e & 7;
        int quad = lane >> 4;
        int nt = tile / 7, tt = tile % 7;
        int col = nt * 16 + (lane & 15);
        float v0, v1;
        if (tt < 6) {
            const float* W = isS ? ((tt < 2) ? sWh : (tt < 4) ? sWa : sWb)
                                 : ((tt < 2) ? nWh : (tt < 4) ? nWa : nWb);
            int k = (tt & 1) * 32 + quad * 8 + j0;
            v0 = W[k * 256 + col]; v1 = W[(k + 1) * 256 + col];
        } else {
            int kl = quad * 8 + j0;
            auto xv = [&](int k) -> float {
                if (!isS) { if (k < 3) return nWx[k * 256 + col]; if (k == 3) return nb[col]; return 0.f; }
                else      { if (k == 4) return sWx[col]; if (k == 5) return sb[col]; return 0.f; }
            };
            v0 = xv(kl); v1 = xv(kl + 1);
        }
        wsu[(isS ? OFF_SPK : OFF_NPK) + dn] = pack2(v0, v1);
    } else {
        int dd = idx - 2 * NPK_DW;
        int tile = dd >> 8;
        int e = (dd & 255) * 2;
        int lane = e >> 3, j0 = e & 7;
        int quad = lane >> 4;
        int nt = tile >> 4, tt = tile & 15;
        const float* W = (tt < 4) ? dWx : (tt < 8) ? dWh : (tt < 12) ? dWa : dWb;
        int k = (tt & 3) * 32 + quad * 8 + j0;
        int col = nt * 16 + (lane & 15);
        wsu[OFF_DPK + dd] = pack2(W[k * 512 + col], W[(k + 1) * 512 + col]);
    }
}

// Persistent cooperative kernel: loop over li=0..127 with one grid-wide sync per
// epoch. Blocks 0-127 run phase A of step t=li (n/s cells + dWx@dec gate partials);
// blocks 128-255 run phase B of step t=li-1 (dWh/dWa/dWb + epilogue + heads).
// c-state lives in registers across epochs (was a global round-trip per step).
__global__ __launch_bounds__(TB) void pipe_persist(
    const float* __restrict__ input,
    const float* __restrict__ db,
    const float* __restrict__ onW, const float* __restrict__ onb,
    const float* __restrict__ osW, const float* __restrict__ osb,
    float* __restrict__ ws)
{
    cg::grid_group grid = cg::this_grid();

    const int tid = threadIdx.x;
    const int wave = tid >> 6, lane = tid & 63;
    const int quad = lane >> 4, l15 = lane & 15;
    const int blk = blockIdx.x;

    _Float16* hnG = (_Float16*)((unsigned int*)ws + OFF_HN);
    _Float16* hsG = (_Float16*)((unsigned int*)ws + OFF_HS);
    _Float16* hdG = (_Float16*)((unsigned int*)ws + OFF_HD);
    float* gpart = ws + OFF_GP;
    float* outs = ws + OFF_OUTS;
    const _Float16* pd = (const _Float16*)((const unsigned int*)ws + OFF_DPK);

    __shared__ __align__(16) _Float16 sh_hn[18 * 72];
    __shared__ __align__(16) _Float16 sh_hs[18 * 72];
    __shared__ __align__(16) _Float16 sh_xa[16 * 40];
    __shared__ __align__(16) _Float16 sh_dec[16 * 136];
    __shared__ __align__(16) _Float16 sh_hd[18 * 136];
    __shared__ float sh_hdnew[16 * 128];

    // persistent per-lane cell state (one float4 per (block, wave, lane))
    float4v creg = (float4v){0.f, 0.f, 0.f, 0.f};

    const bool isA = (blk < 128);
    // role-invariant precompute
    const int ab = isA ? blk : (blk - 128);
    const int r0 = ab * RPB;
    const bool leftOK = (ab & 7) != 0;
    const bool rightOK = (ab & 7) != 7;

    for (int li = 0; li <= NSTEPS; ++li) {
        if (isA) {
            // ================= A role: step t = li =================
            if (li <= 126) {
                const int b = r0 >> 7;
                const int s0 = r0 & 127;
                const int pin = (li + 1) & 1, pout = li & 1;
                const _Float16* hnC = hnG + (size_t)pin * ROWS * 64;
                const _Float16* hsC = hsG + (size_t)pin * ROWS * 64;
                _Float16* hnN = hnG + (size_t)pout * ROWS * 64;
                _Float16* hsN = hsG + (size_t)pout * ROWS * 64;

                // stage hn/hs (+/-1 halo rows)
                for (int i = tid; i < 1152; i += TB) {
                    bool isHs = i >= 576;
                    int j = isHs ? i - 576 : i;
                    int row = j >> 5, p = j & 31;
                    int grow = r0 + row - 1;
                    bool v = (row == 0) ? leftOK : ((row == 17) ? rightOK : true);
                    const _Float16* src = isHs ? hsC : hnC;
                    unsigned int val = v ? ((const unsigned int*)src)[(size_t)grow * 32 + p] : 0u;
                    _Float16* dst = isHs ? sh_hs : sh_hn;
                    *(unsigned int*)(dst + row * 72 + 2 * p) = val;
                }
                for (int i = tid; i < 272; i += TB) {
                    int r = i / 17, d = 3 + (i % 17);
                    ((unsigned int*)sh_xa)[r * 20 + d] = 0u;
                }
                if (tid < 16) {
                    const float* xp = input + ((size_t)(b * T_ + li) * S_ + (s0 + tid)) * 4;
                    unsigned int* row = (unsigned int*)sh_xa + tid * 20;
                    row[0] = pack2(xp[0], xp[1]);
                    row[1] = pack2(xp[2], 1.f);
                    row[2] = pack2(xp[3], 1.f);
                }
                __syncthreads();

                // phase A MFMA: waves 0-3 n-cell, 4-7 s-cell (16-col sub per wave)
                {
                    const int subA = wave & 3;
                    const bool isS = (wave >= 4);
                    const _Float16* hb = isS ? sh_hs : sh_hn;
                    const _Float16* pk = (const _Float16*)((const unsigned int*)ws + (isS ? OFF_SPK : OFF_NPK));
                    half8 ah0 = *(const half8*)(hb + (l15 + 1) * 72 + quad * 8);
                    half8 ah1 = *(const half8*)(hb + (l15 + 1) * 72 + 32 + quad * 8);
                    half8 aa0 = *(const half8*)(hb + (l15 + 2) * 72 + quad * 8);
                    half8 aa1 = *(const half8*)(hb + (l15 + 2) * 72 + 32 + quad * 8);
                    half8 ab0 = *(const half8*)(hb + (l15) * 72 + quad * 8);
                    half8 ab1 = *(const half8*)(hb + (l15) * 72 + 32 + quad * 8);
                    half8 ax  = *(const half8*)(sh_xa + l15 * 40 + quad * 8);
                    float4v acc[4];
#pragma unroll
                    for (int g = 0; g < 4; ++g) acc[g] = (float4v){0.f, 0.f, 0.f, 0.f};
#pragma unroll
                    for (int g = 0; g < 4; ++g) {
                        const _Float16* base = pk + (size_t)(4 * g + subA) * 7 * 512 + lane * 8;
                        acc[g] = __builtin_amdgcn_mfma_f32_16x16x32_f16(ah0, *(const half8*)(base),        acc[g], 0, 0, 0);
                        acc[g] = __builtin_amdgcn_mfma_f32_16x16x32_f16(ah1, *(const half8*)(base + 512),  acc[g], 0, 0, 0);
                        acc[g] = __builtin_amdgcn_mfma_f32_16x16x32_f16(aa0, *(const half8*)(base + 1024), acc[g], 0, 0, 0);
                        acc[g] = __builtin_amdgcn_mfma_f32_16x16x32_f16(aa1, *(const half8*)(base + 1536), acc[g], 0, 0, 0);
                        acc[g] = __builtin_amdgcn_mfma_f32_16x16x32_f16(ab0, *(const half8*)(base + 2048), acc[g], 0, 0, 0);
                        acc[g] = __builtin_amdgcn_mfma_f32_16x16x32_f16(ab1, *(const half8*)(base + 2560), acc[g], 0, 0, 0);
                        acc[g] = __builtin_amdgcn_mfma_f32_16x16x32_f16(ax,  *(const half8*)(base + 3072), acc[g], 0, 0, 0);
                    }
                    float4v cold = creg;
                    float4v cnew;
                    _Float16* hN = isS ? hsN : hnN;
                    const int kcol = 16 * subA + l15;
#pragma unroll
                    for (int r = 0; r < 4; ++r) {
                        float c2 = sigm(acc[1][r]) * cold[r] + sigm(acc[0][r]) * tanh_(acc[2][r]);
                        float h2 = sigm(acc[3][r]) * tanh_(c2);
                        cnew[r] = c2;
                        int row = quad * 4 + r;
                        hN[(size_t)(r0 + row) * 64 + kcol] = (_Float16)h2;
                        sh_dec[row * 136 + (isS ? 64 : 0) + kcol] = (_Float16)h2;
                    }
                    creg = cnew;
                }
                __syncthreads();

                // dWx @ dec gate partials (all 8 waves; ct = wave covers 128 d-cols)
                {
                    const int ct = wave;
                    half8 aD[4];
#pragma unroll
                    for (int kt = 0; kt < 4; ++kt)
                        aD[kt] = *(const half8*)(sh_dec + l15 * 136 + kt * 32 + quad * 8);
                    float4v accP[4];
#pragma unroll
                    for (int g = 0; g < 4; ++g) accP[g] = (float4v){0.f, 0.f, 0.f, 0.f};
#pragma unroll
                    for (int g = 0; g < 4; ++g) {
                        const _Float16* base = pd + (size_t)(g * 8 + ct) * 16 * 512 + lane * 8;
#pragma unroll
                        for (int kt = 0; kt < 4; ++kt)
                            accP[g] = __builtin_amdgcn_mfma_f32_16x16x32_f16(aD[kt], *(const half8*)(base + kt * 512), accP[g], 0, 0, 0);
                    }
                    float* gp = gpart + ((((size_t)(li & 1) * 128 + ab) * 8 + ct) * 4) * 256;
#pragma unroll
                    for (int g = 0; g < 4; ++g)
                        *(float4v*)&gp[g * 256 + lane * 4] = accP[g];
                }
            }
        } else {
            // ================= B role: step t = li-1 =================
            if (li >= 1) {
                const int bb = ab;
                const int t = li - 1;
                const int pinD = li & 1;           // hd(t-1) parity
                const int poutD = (li + 1) & 1;    // hd(t) parity
                const _Float16* hdC = hdG + (size_t)pinD * ROWS * 128;
                _Float16* hdN = hdG + (size_t)poutD * ROWS * 128;

                for (int i = tid; i < 1152; i += TB) {
                    int row = i >> 6, p = i & 63;
                    int grow = r0 + row - 1;
                    bool v = (row == 0) ? leftOK : ((row == 17) ? rightOK : true);
                    unsigned int val = v ? ((const unsigned int*)hdC)[(size_t)grow * 64 + p] : 0u;
                    *(unsigned int*)(sh_hd + row * 136 + 2 * p) = val;
                }
                __syncthreads();

                {
                    const int ct = wave;
                    // init acc from A's dWx partials (written last epoch)
                    const float* gp = gpart + ((((size_t)((li + 1) & 1) * 128 + bb) * 8 + ct) * 4) * 256;
                    float4v acc[4];
#pragma unroll
                    for (int g = 0; g < 4; ++g) acc[g] = *(const float4v*)&gp[g * 256 + lane * 4];
                    half8 aH[4], aA[4], aB4[4];
#pragma unroll
                    for (int kt = 0; kt < 4; ++kt) {
                        aH[kt]  = *(const half8*)(sh_hd + (l15 + 1) * 136 + kt * 32 + quad * 8);
                        aA[kt]  = *(const half8*)(sh_hd + (l15 + 2) * 136 + kt * 32 + quad * 8);
                        aB4[kt] = *(const half8*)(sh_hd + (l15) * 136 + kt * 32 + quad * 8);
                    }
#pragma unroll
                    for (int g = 0; g < 4; ++g) {
                        const _Float16* base = pd + (size_t)(g * 8 + ct) * 16 * 512 + lane * 8;
#pragma unroll
                        for (int kt = 0; kt < 4; ++kt)
                            acc[g] = __builtin_amdgcn_mfma_f32_16x16x32_f16(aH[kt], *(const half8*)(base + (4 + kt) * 512), acc[g], 0, 0, 0);
#pragma unroll
                        for (int kt = 0; kt < 4; ++kt)
                            acc[g] = __builtin_amdgcn_mfma_f32_16x16x32_f16(aA[kt], *(const half8*)(base + (8 + kt) * 512), acc[g], 0, 0, 0);
#pragma unroll
                        for (int kt = 0; kt < 4; ++kt)
                            acc[g] = __builtin_amdgcn_mfma_f32_16x16x32_f16(aB4[kt], *(const half8*)(base + (12 + kt) * 512), acc[g], 0, 0, 0);
                    }
                    const int kd = 16 * ct + l15;
                    float bi = db[kd], bf = db[128 + kd], bu = db[256 + kd], bo = db[384 + kd];
                    float4v cold = creg, cnew;
#pragma unroll
                    for (int r = 0; r < 4; ++r) {
                        float c2 = sigm(acc[1][r] + bf) * cold[r] + sigm(acc[0][r] + bi) * tanh_(acc[2][r] + bu);
                        float h2 = sigm(acc[3][r] + bo) * tanh_(c2);
                        cnew[r] = c2;
                        int row = quad * 4 + r;
                        hdN[(size_t)(r0 + row) * 128 + kd] = (_Float16)h2;
                        sh_hdnew[row * 128 + kd] = h2;
                    }
                    creg = cnew;
                }
                __syncthreads();

                // output heads for step t
                {
                    int p = tid >> 4, l16 = tid & 15;
                    int row = p >> 1, head = p & 1;
                    const float* W = head ? osW : onW;
                    float partial = 0.f;
#pragma unroll
                    for (int k = 0; k < 128; k += 16) partial += sh_hdnew[row * 128 + k + l16] * W[k + l16];
#pragma unroll
                    for (int off = 8; off; off >>= 1) partial += __shfl_down(partial, off, 16);
                    if (l16 == 0)
                        outs[((size_t)t * ROWS + (r0 + row)) * 2 + head] = partial + (head ? osb[0] : onb[0]);
                }
            }
        }
        grid.sync();
    }
}

// Assemble data outputs for t in [20,126] (head biases already in outs).
__global__ __launch_bounds__(256) void assemble_kernel(
    const float* __restrict__ input, const float* __restrict__ ws, float* __restrict__ out)
{
    const float* outs = ws + OFF_OUTS;
    int idx = blockIdx.x * 256 + threadIdx.x;  // (b, tt, s)
    if (idx >= B_ * TOUT * S_) return;
    int s = idx & 127;
    int tmp = idx >> 7;
    int tt = tmp % TOUT;
    int b = tmp / TOUT;
    int t = tt + TPRED;
    int row = b * S_ + s;
    float o0 = outs[((size_t)t * ROWS + row) * 2 + 0];
    float o1 = outs[((size_t)t * ROWS + row) * 2 + 1];
    float inflow = (s == 0) ? input[(((size_t)b * T_ + (t + 1)) * S_ + 0) * 4 + 1]
                            : outs[((size_t)t * ROWS + row - 1) * 2 + 0];
    float numc = input[(((size_t)b * T_ + t) * S_ + s) * 4 + 2] + inflow - o0;
    float spd = (s == 0) ? input[(((size_t)b * T_ + (t + 1)) * S_ + 0) * 4 + 3] : o1;
    float4 v = make_float4(o0, inflow, numc, spd);
    reinterpret_cast<float4*>(out)[idx] = v;
}

extern "C" void kernel_launch(void* const* d_in, const int* in_sizes, int n_in,
                              void* d_out, int out_size, void* d_ws, size_t ws_size,
                              hipStream_t stream) {
    const float* input = (const float*)d_in[0];
    const float* nWx = (const float*)d_in[1];
    const float* nWh = (const float*)d_in[2];
    const float* nWa = (const float*)d_in[3];
    const float* nWb = (const float*)d_in[4];
    const float* nb  = (const float*)d_in[5];
    const float* sWx = (const float*)d_in[6];
    const float* sWh = (const float*)d_in[7];
    const float* sWa = (const float*)d_in[8];
    const float* sWb = (const float*)d_in[9];
    const float* sb  = (const float*)d_in[10];
    const float* dWx = (const float*)d_in[11];
    const float* dWh = (const float*)d_in[12];
    const float* dWa = (const float*)d_in[13];
    const float* dWb = (const float*)d_in[14];
    const float* db  = (const float*)d_in[15];
    const float* onW = (const float*)d_in[16];
    const float* onb = (const float*)d_in[17];
    const float* osW = (const float*)d_in[18];
    const float* osb = (const float*)d_in[19];

    float* ws = (float*)d_ws;

    // zero h buffers (both parities); c-state is register-resident now
    hipMemsetAsync(ws, 0, (size_t)ZERO_DW * 4, stream);

    // pack weights into MFMA B-fragment tiles (once per call)
    pack_weights<<<dim3((PACK_DWORDS + 255) / 256), dim3(256), 0, stream>>>(
        nWx, nWh, nWa, nWb, nb, sWx, sWh, sWa, sWb, sb,
        dWx, dWh, dWa, dWb, (unsigned int*)ws);

    // single persistent cooperative launch replacing 128 per-step launches
    void* kargs[] = {
        (void*)&input, (void*)&db, (void*)&onW, (void*)&onb,
        (void*)&osW, (void*)&osb, (void*)&ws
    };
    hipLaunchCooperativeKernel((void*)pipe_persist, dim3(NBLK), dim3(TB),
                               kargs, 0, stream);

    int nout = B_ * TOUT * S_;
    assemble_kernel<<<dim3((nout + 255) / 256), dim3(256), 0, stream>>>(input, ws, (float*)d_out);
}

// Round 3
// 2598.981 us; speedup vs baseline: 1.9986x; 1.9986x over previous
//
#include <hip/hip_runtime.h>

// Problem constants (from reference)
constexpr int B_ = 16, T_ = 128, S_ = 128;
constexpr int ROWS = B_ * S_;        // 2048
constexpr int NSTEPS = T_ - 1;       // 127
constexpr int TPRED = 20;
constexpr int TOUT = NSTEPS - TPRED; // 107
constexpr int RPB = 16;              // rows per row-tile (MFMA M)
constexpr int TB = 512;              // 8 waves
constexpr int NBLK = 256;            // 128 A-role + 128 B-role blocks

// ws layout in 4-byte units.
constexpr int OFF_HN = 0;                       // [2][2048][64] f16 (parity = step&1)
constexpr int OFF_HS = OFF_HN + 131072;
constexpr int OFF_HD = OFF_HS + 131072;         // [2][2048][128] f16
constexpr int OFF_BAR = OFF_HD + 262144;        // barrier counter (in zeroed region)
constexpr int OFF_GP = OFF_BAR + 262144 + 262144; // gpart[2][128][8][4][64][4] f32
constexpr int OFF_OUTS = OFF_GP + 2097152;      // outs[127][2048][2] f32
constexpr int ZERO_DW = OFF_GP;                 // zero h + barrier region
// packed fp16 weight fragments
constexpr int OFF_NPK = OFF_OUTS + NSTEPS * ROWS * 2;
constexpr int NPK_DW = 16 * 7 * 256;            // 28672
constexpr int OFF_SPK = OFF_NPK + NPK_DW;
constexpr int OFF_DPK = OFF_SPK + NPK_DW;       // 32 nt * 16 tiles * 256 dw
constexpr int DPK_DW = 32 * 16 * 256;           // 131072
constexpr int PACK_DWORDS = 2 * NPK_DW + DPK_DW;

typedef _Float16 half8 __attribute__((ext_vector_type(8)));
typedef float float4v __attribute__((ext_vector_type(4)));

__device__ __forceinline__ float sigm(float x) { return 1.f / (1.f + __expf(-x)); }
__device__ __forceinline__ float tanh_(float x) { return 2.f / (1.f + __expf(-2.f * x)) - 1.f; }
__device__ __forceinline__ unsigned int pack2(float a, float b) {
    union { unsigned int u; _Float16 h[2]; } x;
    x.h[0] = (_Float16)a; x.h[1] = (_Float16)b; return x.u;
}

// ---- device-coherent (cross-XCD) access helpers: relaxed agent-scope atomics
// compile to L1/L2-bypassing (sc0 sc1) loads/stores hitting the coherent L3.
// No acquire/release fences anywhere -> no buffer_inv / buffer_wbl2 -> weights
// stay cached in per-XCD L2 across all epochs.
__device__ __forceinline__ unsigned ld_dev_u32(const unsigned* p) {
    return __hip_atomic_load(p, __ATOMIC_RELAXED, __HIP_MEMORY_SCOPE_AGENT);
}
__device__ __forceinline__ void st_dev_u32(unsigned* p, unsigned v) {
    __hip_atomic_store(p, v, __ATOMIC_RELAXED, __HIP_MEMORY_SCOPE_AGENT);
}
__device__ __forceinline__ void st_dev_f16(_Float16* p, _Float16 v) {
    __hip_atomic_store(p, v, __ATOMIC_RELAXED, __HIP_MEMORY_SCOPE_AGENT);
}
__device__ __forceinline__ float4v ld_dev_f4(const float* p) {
    union { float4v f; unsigned long long u[2]; } cv;
    cv.u[0] = __hip_atomic_load((const unsigned long long*)p, __ATOMIC_RELAXED, __HIP_MEMORY_SCOPE_AGENT);
    cv.u[1] = __hip_atomic_load((const unsigned long long*)p + 1, __ATOMIC_RELAXED, __HIP_MEMORY_SCOPE_AGENT);
    return cv.f;
}
__device__ __forceinline__ void st_dev_f4(float* p, float4v v) {
    union { float4v f; unsigned long long u[2]; } cv;
    cv.f = v;
    __hip_atomic_store((unsigned long long*)p, cv.u[0], __ATOMIC_RELAXED, __HIP_MEMORY_SCOPE_AGENT);
    __hip_atomic_store((unsigned long long*)p + 1, cv.u[1], __ATOMIC_RELAXED, __HIP_MEMORY_SCOPE_AGENT);
}

// ---- pack fp32 weights into MFMA B-fragment tiles (fp16), once per call ----
__global__ __launch_bounds__(256) void pack_weights(
    const float* __restrict__ nWx, const float* __restrict__ nWh,
    const float* __restrict__ nWa, const float* __restrict__ nWb, const float* __restrict__ nb,
    const float* __restrict__ sWx, const float* __restrict__ sWh,
    const float* __restrict__ sWa, const float* __restrict__ sWb, const float* __restrict__ sb,
    const float* __restrict__ dWx, const float* __restrict__ dWh,
    const float* __restrict__ dWa, const float* __restrict__ dWb,
    unsigned int* __restrict__ wsu)
{
    int idx = blockIdx.x * 256 + threadIdx.x;
    if (idx >= PACK_DWORDS) return;
    if (idx < 2 * NPK_DW) {
        bool isS = idx >= NPK_DW;
        int dn = isS ? idx - NPK_DW : idx;
        int tile = dn >> 8;
        int e = (dn & 255) * 2;
        int lane = e >> 3, j0 = e & 7;
        int quad = lane >> 4;
        int nt = tile / 7, tt = tile % 7;
        int col = nt * 16 + (lane & 15);
        float v0, v1;
        if (tt < 6) {
            const float* W = isS ? ((tt < 2) ? sWh : (tt < 4) ? sWa : sWb)
                                 : ((tt < 2) ? nWh : (tt < 4) ? nWa : nWb);
            int k = (tt & 1) * 32 + quad * 8 + j0;
            v0 = W[k * 256 + col]; v1 = W[(k + 1) * 256 + col];
        } else {
            int kl = quad * 8 + j0;
            auto xv = [&](int k) -> float {
                if (!isS) { if (k < 3) return nWx[k * 256 + col]; if (k == 3) return nb[col]; return 0.f; }
                else      { if (k == 4) return sWx[col]; if (k == 5) return sb[col]; return 0.f; }
            };
            v0 = xv(kl); v1 = xv(kl + 1);
        }
        wsu[(isS ? OFF_SPK : OFF_NPK) + dn] = pack2(v0, v1);
    } else {
        int dd = idx - 2 * NPK_DW;
        int tile = dd >> 8;
        int e = (dd & 255) * 2;
        int lane = e >> 3, j0 = e & 7;
        int quad = lane >> 4;
        int nt = tile >> 4, tt = tile & 15;
        const float* W = (tt < 4) ? dWx : (tt < 8) ? dWh : (tt < 12) ? dWa : dWb;
        int k = (tt & 3) * 32 + quad * 8 + j0;
        int col = nt * 16 + (lane & 15);
        wsu[OFF_DPK + dd] = pack2(W[k * 512 + col], W[(k + 1) * 512 + col]);
    }
}

// Persistent kernel with hand-rolled device barrier (monotonic counter, relaxed
// agent atomics only). Blocks 0-127: phase A of step t=li; blocks 128-255:
// phase B of step t=li-1. c-state in registers.
__global__ __launch_bounds__(TB) void pipe_persist(
    const float* __restrict__ input,
    const float* __restrict__ db,
    const float* __restrict__ onW, const float* __restrict__ onb,
    const float* __restrict__ osW, const float* __restrict__ osb,
    float* __restrict__ ws)
{
    const int tid = threadIdx.x;
    const int wave = tid >> 6, lane = tid & 63;
    const int quad = lane >> 4, l15 = lane & 15;
    const int blk = blockIdx.x;

    _Float16* hnG = (_Float16*)((unsigned int*)ws + OFF_HN);
    _Float16* hsG = (_Float16*)((unsigned int*)ws + OFF_HS);
    _Float16* hdG = (_Float16*)((unsigned int*)ws + OFF_HD);
    unsigned* bar = (unsigned*)ws + OFF_BAR;
    float* gpart = ws + OFF_GP;
    float* outs = ws + OFF_OUTS;
    const _Float16* pd = (const _Float16*)((const unsigned int*)ws + OFF_DPK);

    __shared__ __align__(16) _Float16 sh_hn[18 * 72];
    __shared__ __align__(16) _Float16 sh_hs[18 * 72];
    __shared__ __align__(16) _Float16 sh_xa[16 * 40];
    __shared__ __align__(16) _Float16 sh_dec[16 * 136];
    __shared__ __align__(16) _Float16 sh_hd[18 * 136];
    __shared__ float sh_hdnew[16 * 128];

    // persistent per-lane cell state
    float4v creg = (float4v){0.f, 0.f, 0.f, 0.f};

    const bool isA = (blk < 128);
    const int ab = isA ? blk : (blk - 128);
    const int r0 = ab * RPB;
    const bool leftOK = (ab & 7) != 0;
    const bool rightOK = (ab & 7) != 7;

    for (int li = 0; li <= NSTEPS; ++li) {
        if (isA) {
            // ================= A role: step t = li =================
            if (li <= 126) {
                const int b = r0 >> 7;
                const int s0 = r0 & 127;
                const int pin = (li + 1) & 1, pout = li & 1;
                const _Float16* hnC = hnG + (size_t)pin * ROWS * 64;
                const _Float16* hsC = hsG + (size_t)pin * ROWS * 64;
                _Float16* hnN = hnG + (size_t)pout * ROWS * 64;
                _Float16* hsN = hsG + (size_t)pout * ROWS * 64;

                // stage hn/hs (+/-1 halo rows) via device-coherent loads
                for (int i = tid; i < 1152; i += TB) {
                    bool isHs = i >= 576;
                    int j = isHs ? i - 576 : i;
                    int row = j >> 5, p = j & 31;
                    int grow = r0 + row - 1;
                    bool v = (row == 0) ? leftOK : ((row == 17) ? rightOK : true);
                    const _Float16* src = isHs ? hsC : hnC;
                    unsigned int val = v ? ld_dev_u32((const unsigned*)src + (size_t)grow * 32 + p) : 0u;
                    _Float16* dst = isHs ? sh_hs : sh_hn;
                    *(unsigned int*)(dst + row * 72 + 2 * p) = val;
                }
                for (int i = tid; i < 272; i += TB) {
                    int r = i / 17, d = 3 + (i % 17);
                    ((unsigned int*)sh_xa)[r * 20 + d] = 0u;
                }
                if (tid < 16) {
                    const float* xp = input + ((size_t)(b * T_ + li) * S_ + (s0 + tid)) * 4;
                    unsigned int* row = (unsigned int*)sh_xa + tid * 20;
                    row[0] = pack2(xp[0], xp[1]);
                    row[1] = pack2(xp[2], 1.f);
                    row[2] = pack2(xp[3], 1.f);
                }
                __syncthreads();

                // phase A MFMA: waves 0-3 n-cell, 4-7 s-cell (16-col sub per wave)
                {
                    const int subA = wave & 3;
                    const bool isS = (wave >= 4);
                    const _Float16* hb = isS ? sh_hs : sh_hn;
                    const _Float16* pk = (const _Float16*)((const unsigned int*)ws + (isS ? OFF_SPK : OFF_NPK));
                    half8 ah0 = *(const half8*)(hb + (l15 + 1) * 72 + quad * 8);
                    half8 ah1 = *(const half8*)(hb + (l15 + 1) * 72 + 32 + quad * 8);
                    half8 aa0 = *(const half8*)(hb + (l15 + 2) * 72 + quad * 8);
                    half8 aa1 = *(const half8*)(hb + (l15 + 2) * 72 + 32 + quad * 8);
                    half8 ab0 = *(const half8*)(hb + (l15) * 72 + quad * 8);
                    half8 ab1 = *(const half8*)(hb + (l15) * 72 + 32 + quad * 8);
                    half8 ax  = *(const half8*)(sh_xa + l15 * 40 + quad * 8);
                    float4v acc[4];
#pragma unroll
                    for (int g = 0; g < 4; ++g) acc[g] = (float4v){0.f, 0.f, 0.f, 0.f};
#pragma unroll
                    for (int g = 0; g < 4; ++g) {
                        const _Float16* base = pk + (size_t)(4 * g + subA) * 7 * 512 + lane * 8;
                        acc[g] = __builtin_amdgcn_mfma_f32_16x16x32_f16(ah0, *(const half8*)(base),        acc[g], 0, 0, 0);
                        acc[g] = __builtin_amdgcn_mfma_f32_16x16x32_f16(ah1, *(const half8*)(base + 512),  acc[g], 0, 0, 0);
                        acc[g] = __builtin_amdgcn_mfma_f32_16x16x32_f16(aa0, *(const half8*)(base + 1024), acc[g], 0, 0, 0);
                        acc[g] = __builtin_amdgcn_mfma_f32_16x16x32_f16(aa1, *(const half8*)(base + 1536), acc[g], 0, 0, 0);
                        acc[g] = __builtin_amdgcn_mfma_f32_16x16x32_f16(ab0, *(const half8*)(base + 2048), acc[g], 0, 0, 0);
                        acc[g] = __builtin_amdgcn_mfma_f32_16x16x32_f16(ab1, *(const half8*)(base + 2560), acc[g], 0, 0, 0);
                        acc[g] = __builtin_amdgcn_mfma_f32_16x16x32_f16(ax,  *(const half8*)(base + 3072), acc[g], 0, 0, 0);
                    }
                    float4v cold = creg;
                    float4v cnew;
                    _Float16* hN = isS ? hsN : hnN;
                    const int kcol = 16 * subA + l15;
#pragma unroll
                    for (int r = 0; r < 4; ++r) {
                        float c2 = sigm(acc[1][r]) * cold[r] + sigm(acc[0][r]) * tanh_(acc[2][r]);
                        float h2 = sigm(acc[3][r]) * tanh_(c2);
                        cnew[r] = c2;
                        int row = quad * 4 + r;
                        st_dev_f16(hN + (size_t)(r0 + row) * 64 + kcol, (_Float16)h2);
                        sh_dec[row * 136 + (isS ? 64 : 0) + kcol] = (_Float16)h2;
                    }
                    creg = cnew;
                }
                __syncthreads();

                // dWx @ dec gate partials (all 8 waves; ct = wave covers 128 d-cols)
                {
                    const int ct = wave;
                    half8 aD[4];
#pragma unroll
                    for (int kt = 0; kt < 4; ++kt)
                        aD[kt] = *(const half8*)(sh_dec + l15 * 136 + kt * 32 + quad * 8);
                    float4v accP[4];
#pragma unroll
                    for (int g = 0; g < 4; ++g) accP[g] = (float4v){0.f, 0.f, 0.f, 0.f};
#pragma unroll
                    for (int g = 0; g < 4; ++g) {
                        const _Float16* base = pd + (size_t)(g * 8 + ct) * 16 * 512 + lane * 8;
#pragma unroll
                        for (int kt = 0; kt < 4; ++kt)
                            accP[g] = __builtin_amdgcn_mfma_f32_16x16x32_f16(aD[kt], *(const half8*)(base + kt * 512), accP[g], 0, 0, 0);
                    }
                    float* gp = gpart + ((((size_t)(li & 1) * 128 + ab) * 8 + ct) * 4) * 256;
#pragma unroll
                    for (int g = 0; g < 4; ++g)
                        st_dev_f4(&gp[g * 256 + lane * 4], accP[g]);
                }
            }
        } else {
            // ================= B role: step t = li-1 =================
            if (li >= 1) {
                const int bb = ab;
                const int t = li - 1;
                const int pinD = li & 1;           // hd(t-1) parity
                const int poutD = (li + 1) & 1;    // hd(t) parity
                const _Float16* hdC = hdG + (size_t)pinD * ROWS * 128;
                _Float16* hdN = hdG + (size_t)poutD * ROWS * 128;

                for (int i = tid; i < 1152; i += TB) {
                    int row = i >> 6, p = i & 63;
                    int grow = r0 + row - 1;
                    bool v = (row == 0) ? leftOK : ((row == 17) ? rightOK : true);
                    unsigned int val = v ? ld_dev_u32((const unsigned*)hdC + (size_t)grow * 64 + p) : 0u;
                    *(unsigned int*)(sh_hd + row * 136 + 2 * p) = val;
                }
                __syncthreads();

                {
                    const int ct = wave;
                    // init acc from A's dWx partials (written last epoch)
                    const float* gp = gpart + ((((size_t)((li + 1) & 1) * 128 + bb) * 8 + ct) * 4) * 256;
                    float4v acc[4];
#pragma unroll
                    for (int g = 0; g < 4; ++g) acc[g] = ld_dev_f4(&gp[g * 256 + lane * 4]);
                    half8 aH[4], aA[4], aB4[4];
#pragma unroll
                    for (int kt = 0; kt < 4; ++kt) {
                        aH[kt]  = *(const half8*)(sh_hd + (l15 + 1) * 136 + kt * 32 + quad * 8);
                        aA[kt]  = *(const half8*)(sh_hd + (l15 + 2) * 136 + kt * 32 + quad * 8);
                        aB4[kt] = *(const half8*)(sh_hd + (l15) * 136 + kt * 32 + quad * 8);
                    }
#pragma unroll
                    for (int g = 0; g < 4; ++g) {
                        const _Float16* base = pd + (size_t)(g * 8 + ct) * 16 * 512 + lane * 8;
#pragma unroll
                        for (int kt = 0; kt < 4; ++kt)
                            acc[g] = __builtin_amdgcn_mfma_f32_16x16x32_f16(aH[kt], *(const half8*)(base + (4 + kt) * 512), acc[g], 0, 0, 0);
#pragma unroll
                        for (int kt = 0; kt < 4; ++kt)
                            acc[g] = __builtin_amdgcn_mfma_f32_16x16x32_f16(aA[kt], *(const half8*)(base + (8 + kt) * 512), acc[g], 0, 0, 0);
#pragma unroll
                        for (int kt = 0; kt < 4; ++kt)
                            acc[g] = __builtin_amdgcn_mfma_f32_16x16x32_f16(aB4[kt], *(const half8*)(base + (12 + kt) * 512), acc[g], 0, 0, 0);
                    }
                    const int kd = 16 * ct + l15;
                    float bi = db[kd], bf = db[128 + kd], bu = db[256 + kd], bo = db[384 + kd];
                    float4v cold = creg, cnew;
#pragma unroll
                    for (int r = 0; r < 4; ++r) {
                        float c2 = sigm(acc[1][r] + bf) * cold[r] + sigm(acc[0][r] + bi) * tanh_(acc[2][r] + bu);
                        float h2 = sigm(acc[3][r] + bo) * tanh_(c2);
                        cnew[r] = c2;
                        int row = quad * 4 + r;
                        st_dev_f16(hdN + (size_t)(r0 + row) * 128 + kd, (_Float16)h2);
                        sh_hdnew[row * 128 + kd] = h2;
                    }
                    creg = cnew;
                }
                __syncthreads();

                // output heads for step t (outs only read by assemble_kernel later)
                {
                    int p = tid >> 4, l16 = tid & 15;
                    int row = p >> 1, head = p & 1;
                    const float* W = head ? osW : onW;
                    float partial = 0.f;
#pragma unroll
                    for (int k = 0; k < 128; k += 16) partial += sh_hdnew[row * 128 + k + l16] * W[k + l16];
#pragma unroll
                    for (int off = 8; off; off >>= 1) partial += __shfl_down(partial, off, 16);
                    if (l16 == 0)
                        outs[((size_t)t * ROWS + (r0 + row)) * 2 + head] = partial + (head ? osb[0] : onb[0]);
                }
            }
        }

        // ---- device barrier: monotonic counter, no cache maintenance ----
        __syncthreads();   // drains vmcnt(0): all block's device stores complete
        if (tid == 0) {
            asm volatile("s_waitcnt vmcnt(0)" ::: "memory");  // belt & braces
            __hip_atomic_fetch_add(bar, 1u, __ATOMIC_RELAXED, __HIP_MEMORY_SCOPE_AGENT);
            const unsigned target = (unsigned)NBLK * (unsigned)(li + 1);
            while (__hip_atomic_load(bar, __ATOMIC_RELAXED, __HIP_MEMORY_SCOPE_AGENT) < target) {
                __builtin_amdgcn_s_sleep(1);
            }
        }
        __syncthreads();   // release whole block once tid0 observed the epoch
    }
}

// Assemble data outputs for t in [20,126] (head biases already in outs).
__global__ __launch_bounds__(256) void assemble_kernel(
    const float* __restrict__ input, const float* __restrict__ ws, float* __restrict__ out)
{
    const float* outs = ws + OFF_OUTS;
    int idx = blockIdx.x * 256 + threadIdx.x;  // (b, tt, s)
    if (idx >= B_ * TOUT * S_) return;
    int s = idx & 127;
    int tmp = idx >> 7;
    int tt = tmp % TOUT;
    int b = tmp / TOUT;
    int t = tt + TPRED;
    int row = b * S_ + s;
    float o0 = outs[((size_t)t * ROWS + row) * 2 + 0];
    float o1 = outs[((size_t)t * ROWS + row) * 2 + 1];
    float inflow = (s == 0) ? input[(((size_t)b * T_ + (t + 1)) * S_ + 0) * 4 + 1]
                            : outs[((size_t)t * ROWS + row - 1) * 2 + 0];
    float numc = input[(((size_t)b * T_ + t) * S_ + s) * 4 + 2] + inflow - o0;
    float spd = (s == 0) ? input[(((size_t)b * T_ + (t + 1)) * S_ + 0) * 4 + 3] : o1;
    float4 v = make_float4(o0, inflow, numc, spd);
    reinterpret_cast<float4*>(out)[idx] = v;
}

extern "C" void kernel_launch(void* const* d_in, const int* in_sizes, int n_in,
                              void* d_out, int out_size, void* d_ws, size_t ws_size,
                              hipStream_t stream) {
    const float* input = (const float*)d_in[0];
    const float* nWx = (const float*)d_in[1];
    const float* nWh = (const float*)d_in[2];
    const float* nWa = (const float*)d_in[3];
    const float* nWb = (const float*)d_in[4];
    const float* nb  = (const float*)d_in[5];
    const float* sWx = (const float*)d_in[6];
    const float* sWh = (const float*)d_in[7];
    const float* sWa = (const float*)d_in[8];
    const float* sWb = (const float*)d_in[9];
    const float* sb  = (const float*)d_in[10];
    const float* dWx = (const float*)d_in[11];
    const float* dWh = (const float*)d_in[12];
    const float* dWa = (const float*)d_in[13];
    const float* dWb = (const float*)d_in[14];
    const float* db  = (const float*)d_in[15];
    const float* onW = (const float*)d_in[16];
    const float* onb = (const float*)d_in[17];
    const float* osW = (const float*)d_in[18];
    const float* osb = (const float*)d_in[19];

    float* ws = (float*)d_ws;

    // zero h buffers (both parities) + barrier counter region
    hipMemsetAsync(ws, 0, (size_t)ZERO_DW * 4, stream);

    // pack weights into MFMA B-fragment tiles (once per call)
    pack_weights<<<dim3((PACK_DWORDS + 255) / 256), dim3(256), 0, stream>>>(
        nWx, nWh, nWa, nWb, nb, sWx, sWh, sWa, sWb, sb,
        dWx, dWh, dWa, dWb, (unsigned int*)ws);

    // cooperative launch (for co-residency guarantee); sync is hand-rolled inside
    void* kargs[] = {
        (void*)&input, (void*)&db, (void*)&onW, (void*)&onb,
        (void*)&osW, (void*)&osb, (void*)&ws
    };
    hipLaunchCooperativeKernel((void*)pipe_persist, dim3(NBLK), dim3(TB),
                               kargs, 0, stream);

    int nout = B_ * TOUT * S_;
    assemble_kernel<<<dim3((nout + 255) / 256), dim3(256), 0, stream>>>(input, ws, (float*)d_out);
}

// Round 4
// 2175.251 us; speedup vs baseline: 2.3880x; 1.1948x over previous
//
#include <hip/hip_runtime.h>

// Problem constants (from reference)
constexpr int B_ = 16, T_ = 128, S_ = 128;
constexpr int ROWS = B_ * S_;        // 2048
constexpr int NSTEPS = T_ - 1;       // 127
constexpr int TPRED = 20;
constexpr int TOUT = NSTEPS - TPRED; // 107
constexpr int RPB = 16;              // rows per block (MFMA M)
constexpr int TB = 512;              // 8 waves
constexpr int NBLK = 128;            // single-role: one block per 16 rows

// ws layout in 4-byte units (kept compatible with pack_weights).
constexpr int OFF_HN = 0;                       // [2][2048][64] f16 (parity = step&1)
constexpr int OFF_HS = OFF_HN + 131072;
constexpr int OFF_HD = OFF_HS + 131072;         // [2][2048][128] f16
constexpr int OFF_BAR = OFF_HD + 262144;        // prog[128] counters, stride 16 dw
constexpr int OFF_GP = OFF_BAR + 262144 + 262144; // (unused now)
constexpr int OFF_OUTS = OFF_GP + 2097152;      // outs[127][2048][2] f32
constexpr int ZERO_DW = OFF_GP;                 // zero h + prog region
// packed fp16 weight fragments
constexpr int OFF_NPK = OFF_OUTS + NSTEPS * ROWS * 2;
constexpr int NPK_DW = 16 * 7 * 256;            // 28672
constexpr int OFF_SPK = OFF_NPK + NPK_DW;
constexpr int OFF_DPK = OFF_SPK + NPK_DW;       // 32 nt * 16 tiles * 256 dw
constexpr int DPK_DW = 32 * 16 * 256;           // 131072
constexpr int PACK_DWORDS = 2 * NPK_DW + DPK_DW;

typedef _Float16 half8 __attribute__((ext_vector_type(8)));
typedef float float4v __attribute__((ext_vector_type(4)));

__device__ __forceinline__ float sigm(float x) { return 1.f / (1.f + __expf(-x)); }
__device__ __forceinline__ float tanh_(float x) { return 2.f / (1.f + __expf(-2.f * x)) - 1.f; }
__device__ __forceinline__ unsigned int pack2(float a, float b) {
    union { unsigned int u; _Float16 h[2]; } x;
    x.h[0] = (_Float16)a; x.h[1] = (_Float16)b; return x.u;
}

// device-coherent (cross-XCD) helpers: relaxed agent-scope atomics bypass the
// per-XCD L2 and hit the coherent memory-side cache. No acquire/release fences
// -> no buffer_inv/wbl2 -> weights stay L2-resident across epochs.
__device__ __forceinline__ unsigned ld_dev_u32(const unsigned* p) {
    return __hip_atomic_load(p, __ATOMIC_RELAXED, __HIP_MEMORY_SCOPE_AGENT);
}
__device__ __forceinline__ void st_dev_u32(unsigned* p, unsigned v) {
    __hip_atomic_store(p, v, __ATOMIC_RELAXED, __HIP_MEMORY_SCOPE_AGENT);
}
__device__ __forceinline__ void st_dev_f16(_Float16* p, _Float16 v) {
    __hip_atomic_store(p, v, __ATOMIC_RELAXED, __HIP_MEMORY_SCOPE_AGENT);
}

// ---- pack fp32 weights into MFMA B-fragment tiles (fp16), once per call ----
__global__ __launch_bounds__(256) void pack_weights(
    const float* __restrict__ nWx, const float* __restrict__ nWh,
    const float* __restrict__ nWa, const float* __restrict__ nWb, const float* __restrict__ nb,
    const float* __restrict__ sWx, const float* __restrict__ sWh,
    const float* __restrict__ sWa, const float* __restrict__ sWb, const float* __restrict__ sb,
    const float* __restrict__ dWx, const float* __restrict__ dWh,
    const float* __restrict__ dWa, const float* __restrict__ dWb,
    unsigned int* __restrict__ wsu)
{
    int idx = blockIdx.x * 256 + threadIdx.x;
    if (idx >= PACK_DWORDS) return;
    if (idx < 2 * NPK_DW) {
        bool isS = idx >= NPK_DW;
        int dn = isS ? idx - NPK_DW : idx;
        int tile = dn >> 8;
        int e = (dn & 255) * 2;
        int lane = e >> 3, j0 = e & 7;
        int quad = lane >> 4;
        int nt = tile / 7, tt = tile % 7;
        int col = nt * 16 + (lane & 15);
        float v0, v1;
        if (tt < 6) {
            const float* W = isS ? ((tt < 2) ? sWh : (tt < 4) ? sWa : sWb)
                                 : ((tt < 2) ? nWh : (tt < 4) ? nWa : nWb);
            int k = (tt & 1) * 32 + quad * 8 + j0;
            v0 = W[k * 256 + col]; v1 = W[(k + 1) * 256 + col];
        } else {
            int kl = quad * 8 + j0;
            auto xv = [&](int k) -> float {
                if (!isS) { if (k < 3) return nWx[k * 256 + col]; if (k == 3) return nb[col]; return 0.f; }
                else      { if (k == 4) return sWx[col]; if (k == 5) return sb[col]; return 0.f; }
            };
            v0 = xv(kl); v1 = xv(kl + 1);
        }
        wsu[(isS ? OFF_SPK : OFF_NPK) + dn] = pack2(v0, v1);
    } else {
        int dd = idx - 2 * NPK_DW;
        int tile = dd >> 8;
        int e = (dd & 255) * 2;
        int lane = e >> 3, j0 = e & 7;
        int quad = lane >> 4;
        int nt = tile >> 4, tt = tile & 15;
        const float* W = (tt < 4) ? dWx : (tt < 8) ? dWh : (tt < 12) ? dWa : dWb;
        int k = (tt & 3) * 32 + quad * 8 + j0;
        int col = nt * 16 + (lane & 15);
        wsu[OFF_DPK + dd] = pack2(W[k * 512 + col], W[(k + 1) * 512 + col]);
    }
}

// Persistent single-role kernel: each block owns 16 rows for all 127 steps.
// All state in parity-double-buffered LDS; cross-block traffic = 1-row halos
// (device-scope relaxed atomics through coherent L3). Sync = 1D neighbor chain
// on per-block monotonic progress counters (skew bounded to 1 epoch, so the
// period-2 parity buffers cannot be clobbered).
__global__ __launch_bounds__(TB) void pipe_persist(
    const float* __restrict__ input,
    const float* __restrict__ db,
    const float* __restrict__ onW, const float* __restrict__ onb,
    const float* __restrict__ osW, const float* __restrict__ osb,
    float* __restrict__ ws)
{
    const int tid = threadIdx.x;
    const int wave = tid >> 6, lane = tid & 63;
    const int quad = lane >> 4, l15 = lane & 15;
    const int ab = blockIdx.x;
    const int r0 = ab * RPB;
    const bool leftOK = (ab & 7) != 0;
    const bool rightOK = (ab & 7) != 7;
    const int b = r0 >> 7, s0 = r0 & 127;

    unsigned* hnU = (unsigned*)ws + OFF_HN;     // u32 view, parity stride 65536
    unsigned* hsU = (unsigned*)ws + OFF_HS;
    unsigned* hdU = (unsigned*)ws + OFF_HD;     // parity stride 131072 u32
    _Float16* hnH = (_Float16*)hnU;             // f16 view, parity stride 131072
    _Float16* hsH = (_Float16*)hsU;
    _Float16* hdH = (_Float16*)hdU;             // parity stride 262144 f16
    unsigned* prog = (unsigned*)ws + OFF_BAR;   // per-block counters, stride 16
    float* outs = ws + OFF_OUTS;
    const _Float16* pd = (const _Float16*)((const unsigned int*)ws + OFF_DPK);

    __shared__ __align__(16) _Float16 sh_hn[2 * 18 * 72];   // [parity][row][72]
    __shared__ __align__(16) _Float16 sh_hs[2 * 18 * 72];
    __shared__ __align__(16) _Float16 sh_hd[2 * 18 * 136];
    __shared__ __align__(16) _Float16 sh_xa[16 * 40];
    __shared__ float sh_hdnew[16 * 128];

    // init LDS state to zero (both parities) + xa pad
    for (int i = tid; i < 1296; i += TB) { ((unsigned*)sh_hn)[i] = 0u; ((unsigned*)sh_hs)[i] = 0u; }
    for (int i = tid; i < 2448; i += TB) ((unsigned*)sh_hd)[i] = 0u;
    for (int i = tid; i < 320; i += TB) ((unsigned*)sh_xa)[i] = 0u;

    // persistent per-lane cell state
    float4v cregA = (float4v){0.f, 0.f, 0.f, 0.f};   // n or s cell (by wave role)
    float4v cregD = (float4v){0.f, 0.f, 0.f, 0.f};   // d cell

    // loop-invariant hoists
    const int kd = 16 * wave + l15;
    const float bi = db[kd], bf = db[128 + kd], bu = db[256 + kd], bo = db[384 + kd];
    const int hp = tid >> 4, hl16 = tid & 15;
    const int hrow = hp >> 1, hhead = hp & 1;
    const float* hW = hhead ? osW : onW;
    float hwreg[8];
#pragma unroll
    for (int kk = 0; kk < 8; ++kk) hwreg[kk] = hW[kk * 16 + hl16];
    const float hbias = hhead ? osb[0] : onb[0];

    __syncthreads();

    for (int li = 0; li < NSTEPS; ++li) {
        const int pin = (li + 1) & 1, pout = li & 1;

        // stage x(t) (read-only input; safe before neighbor wait)
        if (tid < 16) {
            const float* xp = input + ((size_t)(b * T_ + li) * S_ + (s0 + tid)) * 4;
            unsigned* row = (unsigned*)sh_xa + tid * 20;
            row[0] = pack2(xp[0], xp[1]);
            row[1] = pack2(xp[2], 1.f);
            row[2] = pack2(xp[3], 1.f);
        }
        // neighbor-chain wait: halos of epoch li need neighbors done with li-1
        if (li > 0) {
            if (tid == 0 && leftOK) {
                while (ld_dev_u32(prog + (ab - 1) * 16) < (unsigned)li) __builtin_amdgcn_s_sleep(2);
            }
            if (tid == 64 && rightOK) {
                while (ld_dev_u32(prog + (ab + 1) * 16) < (unsigned)li) __builtin_amdgcn_s_sleep(2);
            }
        }
        __syncthreads();

        // halo row loads (parity pin): left -> lds row 0, right -> lds row 17
        if (tid < 256) {
            int side = tid >> 7, j = tid & 127;
            int grow = side ? (r0 + 16) : (r0 - 1);
            bool valid = side ? rightOK : leftOK;
            int lrow = side ? 17 : 0;
            if (j < 64) {
                bool isHs = j >= 32; int p = j & 31;
                unsigned v = valid ? ld_dev_u32((isHs ? hsU : hnU) + (size_t)pin * 65536 + (size_t)grow * 32 + p) : 0u;
                *(unsigned*)((isHs ? sh_hs : sh_hn) + pin * 1296 + lrow * 72 + 2 * p) = v;
            } else {
                int p = j - 64;
                unsigned v = valid ? ld_dev_u32(hdU + (size_t)pin * 131072 + (size_t)grow * 64 + p) : 0u;
                *(unsigned*)(sh_hd + pin * 2448 + lrow * 136 + 2 * p) = v;
            }
        }
        __syncthreads();

        // ---- phase A: n cell (waves 0-3) / s cell (waves 4-7) ----
        {
            const int subA = wave & 3;
            const bool isS = (wave >= 4);
            const _Float16* hb = (isS ? sh_hs : sh_hn) + pin * 1296;
            const _Float16* pk = (const _Float16*)((const unsigned int*)ws + (isS ? OFF_SPK : OFF_NPK));
            half8 ah0 = *(const half8*)(hb + (l15 + 1) * 72 + quad * 8);
            half8 ah1 = *(const half8*)(hb + (l15 + 1) * 72 + 32 + quad * 8);
            half8 aa0 = *(const half8*)(hb + (l15 + 2) * 72 + quad * 8);
            half8 aa1 = *(const half8*)(hb + (l15 + 2) * 72 + 32 + quad * 8);
            half8 ab0 = *(const half8*)(hb + (l15) * 72 + quad * 8);
            half8 ab1 = *(const half8*)(hb + (l15) * 72 + 32 + quad * 8);
            half8 ax  = *(const half8*)(sh_xa + l15 * 40 + quad * 8);
            float4v acc[4];
#pragma unroll
            for (int g = 0; g < 4; ++g) acc[g] = (float4v){0.f, 0.f, 0.f, 0.f};
#pragma unroll
            for (int g = 0; g < 4; ++g) {
                const _Float16* base = pk + (size_t)(4 * g + subA) * 7 * 512 + lane * 8;
                acc[g] = __builtin_amdgcn_mfma_f32_16x16x32_f16(ah0, *(const half8*)(base),        acc[g], 0, 0, 0);
                acc[g] = __builtin_amdgcn_mfma_f32_16x16x32_f16(ah1, *(const half8*)(base + 512),  acc[g], 0, 0, 0);
                acc[g] = __builtin_amdgcn_mfma_f32_16x16x32_f16(aa0, *(const half8*)(base + 1024), acc[g], 0, 0, 0);
                acc[g] = __builtin_amdgcn_mfma_f32_16x16x32_f16(aa1, *(const half8*)(base + 1536), acc[g], 0, 0, 0);
                acc[g] = __builtin_amdgcn_mfma_f32_16x16x32_f16(ab0, *(const half8*)(base + 2048), acc[g], 0, 0, 0);
                acc[g] = __builtin_amdgcn_mfma_f32_16x16x32_f16(ab1, *(const half8*)(base + 2560), acc[g], 0, 0, 0);
                acc[g] = __builtin_amdgcn_mfma_f32_16x16x32_f16(ax,  *(const half8*)(base + 3072), acc[g], 0, 0, 0);
            }
            float4v cold = cregA, cnew;
            _Float16* hLds = (isS ? sh_hs : sh_hn) + pout * 1296;
            _Float16* hGlb = (isS ? hsH : hnH) + (size_t)pout * 131072;
            const int kcol = 16 * subA + l15;
#pragma unroll
            for (int r = 0; r < 4; ++r) {
                float c2 = sigm(acc[1][r]) * cold[r] + sigm(acc[0][r]) * tanh_(acc[2][r]);
                float h2 = sigm(acc[3][r]) * tanh_(c2);
                cnew[r] = c2;
                int row = quad * 4 + r;
                hLds[(row + 1) * 72 + kcol] = (_Float16)h2;
                if (row == 0 || row == 15)
                    st_dev_f16(hGlb + (size_t)(r0 + row) * 64 + kcol, (_Float16)h2);
            }
            cregA = cnew;
        }
        __syncthreads();

        // ---- phase B: d cell (all 8 waves; wave = 16-col group) ----
        {
            const int ct = wave;
            const _Float16* hdP = sh_hd + pin * 2448;
            const _Float16* hnP = sh_hn + pout * 1296;
            const _Float16* hsP = sh_hs + pout * 1296;
            half8 aD[4], aH[4], aA[4], aB4[4];
            aD[0] = *(const half8*)(hnP + (l15 + 1) * 72 + quad * 8);
            aD[1] = *(const half8*)(hnP + (l15 + 1) * 72 + 32 + quad * 8);
            aD[2] = *(const half8*)(hsP + (l15 + 1) * 72 + quad * 8);
            aD[3] = *(const half8*)(hsP + (l15 + 1) * 72 + 32 + quad * 8);
#pragma unroll
            for (int kt = 0; kt < 4; ++kt) {
                aH[kt]  = *(const half8*)(hdP + (l15 + 1) * 136 + kt * 32 + quad * 8);
                aA[kt]  = *(const half8*)(hdP + (l15 + 2) * 136 + kt * 32 + quad * 8);
                aB4[kt] = *(const half8*)(hdP + (l15) * 136 + kt * 32 + quad * 8);
            }
            float4v acc[4];
#pragma unroll
            for (int g = 0; g < 4; ++g) acc[g] = (float4v){0.f, 0.f, 0.f, 0.f};
#pragma unroll
            for (int g = 0; g < 4; ++g) {
                const _Float16* base = pd + (size_t)(g * 8 + ct) * 16 * 512 + lane * 8;
#pragma unroll
                for (int kt = 0; kt < 4; ++kt)
                    acc[g] = __builtin_amdgcn_mfma_f32_16x16x32_f16(aD[kt], *(const half8*)(base + kt * 512), acc[g], 0, 0, 0);
#pragma unroll
                for (int kt = 0; kt < 4; ++kt)
                    acc[g] = __builtin_amdgcn_mfma_f32_16x16x32_f16(aH[kt], *(const half8*)(base + (4 + kt) * 512), acc[g], 0, 0, 0);
#pragma unroll
                for (int kt = 0; kt < 4; ++kt)
                    acc[g] = __builtin_amdgcn_mfma_f32_16x16x32_f16(aA[kt], *(const half8*)(base + (8 + kt) * 512), acc[g], 0, 0, 0);
#pragma unroll
                for (int kt = 0; kt < 4; ++kt)
                    acc[g] = __builtin_amdgcn_mfma_f32_16x16x32_f16(aB4[kt], *(const half8*)(base + (12 + kt) * 512), acc[g], 0, 0, 0);
            }
            float4v cold = cregD, cnew;
            _Float16* hLds = sh_hd + pout * 2448;
            _Float16* hGlb = hdH + (size_t)pout * 262144;
#pragma unroll
            for (int r = 0; r < 4; ++r) {
                float c2 = sigm(acc[1][r] + bf) * cold[r] + sigm(acc[0][r] + bi) * tanh_(acc[2][r] + bu);
                float h2 = sigm(acc[3][r] + bo) * tanh_(c2);
                cnew[r] = c2;
                int row = quad * 4 + r;
                hLds[(row + 1) * 136 + kd] = (_Float16)h2;
                if (row == 0 || row == 15)
                    st_dev_f16(hGlb + (size_t)(r0 + row) * 128 + kd, (_Float16)h2);
                sh_hdnew[row * 128 + kd] = h2;
            }
            cregD = cnew;
        }
        __syncthreads();

        // output heads for step t = li
        {
            float partial = 0.f;
#pragma unroll
            for (int kk = 0; kk < 8; ++kk)
                partial += sh_hdnew[hrow * 128 + kk * 16 + hl16] * hwreg[kk];
#pragma unroll
            for (int off = 8; off; off >>= 1) partial += __shfl_down(partial, off, 16);
            if (hl16 == 0)
                outs[((size_t)li * ROWS + (r0 + hrow)) * 2 + hhead] = partial + hbias;
        }
        __syncthreads();   // drains all device stores (per-thread vmcnt before s_barrier)

        if (tid == 0) st_dev_u32(prog + ab * 16, (unsigned)(li + 1));
    }
}

// Assemble data outputs for t in [20,126] (head biases already in outs).
__global__ __launch_bounds__(256) void assemble_kernel(
    const float* __restrict__ input, const float* __restrict__ ws, float* __restrict__ out)
{
    const float* outs = ws + OFF_OUTS;
    int idx = blockIdx.x * 256 + threadIdx.x;  // (b, tt, s)
    if (idx >= B_ * TOUT * S_) return;
    int s = idx & 127;
    int tmp = idx >> 7;
    int tt = tmp % TOUT;
    int b = tmp / TOUT;
    int t = tt + TPRED;
    int row = b * S_ + s;
    float o0 = outs[((size_t)t * ROWS + row) * 2 + 0];
    float o1 = outs[((size_t)t * ROWS + row) * 2 + 1];
    float inflow = (s == 0) ? input[(((size_t)b * T_ + (t + 1)) * S_ + 0) * 4 + 1]
                            : outs[((size_t)t * ROWS + row - 1) * 2 + 0];
    float numc = input[(((size_t)b * T_ + t) * S_ + s) * 4 + 2] + inflow - o0;
    float spd = (s == 0) ? input[(((size_t)b * T_ + (t + 1)) * S_ + 0) * 4 + 3] : o1;
    float4 v = make_float4(o0, inflow, numc, spd);
    reinterpret_cast<float4*>(out)[idx] = v;
}

extern "C" void kernel_launch(void* const* d_in, const int* in_sizes, int n_in,
                              void* d_out, int out_size, void* d_ws, size_t ws_size,
                              hipStream_t stream) {
    const float* input = (const float*)d_in[0];
    const float* nWx = (const float*)d_in[1];
    const float* nWh = (const float*)d_in[2];
    const float* nWa = (const float*)d_in[3];
    const float* nWb = (const float*)d_in[4];
    const float* nb  = (const float*)d_in[5];
    const float* sWx = (const float*)d_in[6];
    const float* sWh = (const float*)d_in[7];
    const float* sWa = (const float*)d_in[8];
    const float* sWb = (const float*)d_in[9];
    const float* sb  = (const float*)d_in[10];
    const float* dWx = (const float*)d_in[11];
    const float* dWh = (const float*)d_in[12];
    const float* dWa = (const float*)d_in[13];
    const float* dWb = (const float*)d_in[14];
    const float* db  = (const float*)d_in[15];
    const float* onW = (const float*)d_in[16];
    const float* onb = (const float*)d_in[17];
    const float* osW = (const float*)d_in[18];
    const float* osb = (const float*)d_in[19];

    float* ws = (float*)d_ws;

    // zero h buffers (both parities) + progress counters
    hipMemsetAsync(ws, 0, (size_t)ZERO_DW * 4, stream);

    // pack weights into MFMA B-fragment tiles (once per call)
    pack_weights<<<dim3((PACK_DWORDS + 255) / 256), dim3(256), 0, stream>>>(
        nWx, nWh, nWa, nWb, nb, sWx, sWh, sWa, sWb, sb,
        dWx, dWh, dWa, dWb, (unsigned int*)ws);

    // cooperative launch (co-residency guarantee); sync is neighbor-chain inside
    void* kargs[] = {
        (void*)&input, (void*)&db, (void*)&onW, (void*)&onb,
        (void*)&osW, (void*)&osb, (void*)&ws
    };
    hipLaunchCooperativeKernel((void*)pipe_persist, dim3(NBLK), dim3(TB),
                               kargs, 0, stream);

    int nout = B_ * TOUT * S_;
    assemble_kernel<<<dim3((nout + 255) / 256), dim3(256), 0, stream>>>(input, ws, (float*)d_out);
}

// Round 5
// 1294.037 us; speedup vs baseline: 4.0141x; 1.6810x over previous
//
#include <hip/hip_runtime.h>

// Problem constants (from reference)
constexpr int B_ = 16, T_ = 128, S_ = 128;
constexpr int ROWS = B_ * S_;        // 2048
constexpr int NSTEPS = T_ - 1;       // 127
constexpr int TPRED = 20;
constexpr int TOUT = NSTEPS - TPRED; // 107
constexpr int TB = 512;              // 8 waves
constexpr int NBLK = 256;            // 64 n + 64 s + 128 d blocks

// ws layout in 4-byte units.
constexpr int OFF_HN = 0;                       // [2][2048][64] f16 (parity = step&1)
constexpr int OFF_HS = OFF_HN + 131072;
constexpr int OFF_HD = OFF_HS + 131072;         // [2][2048][128] f16
constexpr int OFF_BAR = OFF_HD + 262144;        // sync counters (8192 dw)
constexpr int OFF_OUTS = OFF_BAR + 8192;        // outs[127][2048][2] f32 (atomic-accumulated)
constexpr int OFF_NPK = OFF_OUTS + NSTEPS * ROWS * 2;
constexpr int NPK_DW = 16 * 7 * 256;            // 28672
constexpr int OFF_SPK = OFF_NPK + NPK_DW;
constexpr int OFF_DPK = OFF_SPK + NPK_DW;       // 32 nt * 16 tiles * 256 dw
constexpr int DPK_DW = 32 * 16 * 256;           // 131072
constexpr int PACK_DWORDS = 2 * NPK_DW + DPK_DW;
constexpr int ZERO_DW = OFF_NPK;                // zero h, counters, outs

typedef _Float16 half8 __attribute__((ext_vector_type(8)));
typedef float float4v __attribute__((ext_vector_type(4)));

__device__ __forceinline__ float sigm(float x) { return 1.f / (1.f + __expf(-x)); }
__device__ __forceinline__ float tanh_(float x) { return 2.f / (1.f + __expf(-2.f * x)) - 1.f; }
__device__ __forceinline__ unsigned int pack2(float a, float b) {
    union { unsigned int u; _Float16 h[2]; } x;
    x.h[0] = (_Float16)a; x.h[1] = (_Float16)b; return x.u;
}

// device-coherent (cross-XCD) helpers: relaxed agent-scope atomics bypass the
// per-XCD L2 and hit the coherent memory-side cache. No acquire/release fences
// -> no cache maintenance -> LDS-resident weights + local state untouched.
__device__ __forceinline__ unsigned ld_dev_u32(const unsigned* p) {
    return __hip_atomic_load(p, __ATOMIC_RELAXED, __HIP_MEMORY_SCOPE_AGENT);
}
__device__ __forceinline__ unsigned long long ld_dev_u64(const unsigned long long* p) {
    return __hip_atomic_load(p, __ATOMIC_RELAXED, __HIP_MEMORY_SCOPE_AGENT);
}
__device__ __forceinline__ void st_dev_u32(unsigned* p, unsigned v) {
    __hip_atomic_store(p, v, __ATOMIC_RELAXED, __HIP_MEMORY_SCOPE_AGENT);
}
__device__ __forceinline__ void st_dev_f16(_Float16* p, _Float16 v) {
    __hip_atomic_store(p, v, __ATOMIC_RELAXED, __HIP_MEMORY_SCOPE_AGENT);
}
__device__ __forceinline__ void at_add_u32(unsigned* p, unsigned v) {
    __hip_atomic_fetch_add(p, v, __ATOMIC_RELAXED, __HIP_MEMORY_SCOPE_AGENT);
}
__device__ __forceinline__ void at_add_f32(float* p, float v) {
    __hip_atomic_fetch_add(p, v, __ATOMIC_RELAXED, __HIP_MEMORY_SCOPE_AGENT);
}

// ---- pack fp32 weights into MFMA B-fragment tiles (fp16), once per call ----
__global__ __launch_bounds__(256) void pack_weights(
    const float* __restrict__ nWx, const float* __restrict__ nWh,
    const float* __restrict__ nWa, const float* __restrict__ nWb, const float* __restrict__ nb,
    const float* __restrict__ sWx, const float* __restrict__ sWh,
    const float* __restrict__ sWa, const float* __restrict__ sWb, const float* __restrict__ sb,
    const float* __restrict__ dWx, const float* __restrict__ dWh,
    const float* __restrict__ dWa, const float* __restrict__ dWb,
    unsigned int* __restrict__ wsu)
{
    int idx = blockIdx.x * 256 + threadIdx.x;
    if (idx >= PACK_DWORDS) return;
    if (idx < 2 * NPK_DW) {
        bool isS = idx >= NPK_DW;
        int dn = isS ? idx - NPK_DW : idx;
        int tile = dn >> 8;
        int e = (dn & 255) * 2;
        int lane = e >> 3, j0 = e & 7;
        int quad = lane >> 4;
        int nt = tile / 7, tt = tile % 7;
        int col = nt * 16 + (lane & 15);
        float v0, v1;
        if (tt < 6) {
            const float* W = isS ? ((tt < 2) ? sWh : (tt < 4) ? sWa : sWb)
                                 : ((tt < 2) ? nWh : (tt < 4) ? nWa : nWb);
            int k = (tt & 1) * 32 + quad * 8 + j0;
            v0 = W[k * 256 + col]; v1 = W[(k + 1) * 256 + col];
        } else {
            int kl = quad * 8 + j0;
            auto xv = [&](int k) -> float {
                if (!isS) { if (k < 3) return nWx[k * 256 + col]; if (k == 3) return nb[col]; return 0.f; }
                else      { if (k == 4) return sWx[col]; if (k == 5) return sb[col]; return 0.f; }
            };
            v0 = xv(kl); v1 = xv(kl + 1);
        }
        wsu[(isS ? OFF_SPK : OFF_NPK) + dn] = pack2(v0, v1);
    } else {
        int dd = idx - 2 * NPK_DW;
        int tile = dd >> 8;
        int e = (dd & 255) * 2;
        int lane = e >> 3, j0 = e & 7;
        int quad = lane >> 4;
        int nt = tile >> 4, tt = tile & 15;
        const float* W = (tt < 4) ? dWx : (tt < 8) ? dWh : (tt < 12) ? dWa : dWb;
        int k = (tt & 3) * 32 + quad * 8 + j0;
        int col = nt * 16 + (lane & 15);
        wsu[OFF_DPK + dd] = pack2(W[k * 512 + col], W[(k + 1) * 512 + col]);
    }
}

// Weight-stationary persistent pipeline.
// Blocks 0-63: n-cell, 32 rows each, full n-pack in LDS.
// Blocks 64-127: s-cell, 32 rows each, full s-pack in LDS.
// Blocks 128-255: d-cell, (rowgroup rg = batch of 128 rows) x (colslice c of 16
//   h-cols), 64 KB weight slice in LDS, dec/hd staged from L3 each epoch.
// d lags n/s by one epoch. Sync: monotonic counters (relaxed agent atomics).
__global__ __launch_bounds__(TB) void pipe_persist(
    const float* __restrict__ input,
    const float* __restrict__ db,
    const float* __restrict__ onW, const float* __restrict__ onb,
    const float* __restrict__ osW, const float* __restrict__ osb,
    float* __restrict__ ws)
{
    const int tid = threadIdx.x;
    const int wave = tid >> 6, lane = tid & 63;
    const int quad = lane >> 4, l15 = lane & 15;
    const int blk = blockIdx.x;

    unsigned* wsu = (unsigned*)ws;
    unsigned* hnU = wsu + OFF_HN;               // parity stride 65536 u32
    unsigned* hsU = wsu + OFF_HS;
    unsigned* hdU = wsu + OFF_HD;               // parity stride 131072 u32
    _Float16* hnH = (_Float16*)hnU;             // parity stride 131072 f16
    _Float16* hsH = (_Float16*)hsU;
    _Float16* hdH = (_Float16*)hdU;             // parity stride 262144 f16
    unsigned* nsc = wsu + OFF_BAR;              // [16] stride 32: n/s epoch adds
    unsigned* dc  = wsu + OFF_BAR + 1024;       // [16] stride 32: d epoch adds
    unsigned* np  = wsu + OFF_BAR + 2048;       // [64] stride 32: n progress
    unsigned* sp  = wsu + OFF_BAR + 4096;       // [64] stride 32: s progress
    float* outs = ws + OFF_OUTS;

    union SMem {
        struct { _Float16 pk[16 * 7 * 512]; _Float16 hst[2][34][72]; _Float16 xa[32][40]; } ns;
        struct { _Float16 wd[4 * 16 * 512]; _Float16 dec[128][136]; _Float16 hd[130][136]; } d;
    };
    __shared__ __align__(16) SMem sm;

    if (blk < 128) {
        // ================= n / s role =================
        const bool isS = (blk >= 64);
        const int a = isS ? blk - 64 : blk;
        const int rg = a >> 2;                  // batch
        const int r0 = a * 32;
        const int s0 = (a & 3) * 32;
        const bool leftOK = (a & 3) != 0;
        const bool rightOK = (a & 3) != 3;
        unsigned* hU = isS ? hsU : hnU;
        _Float16* hH = isS ? hsH : hnH;
        unsigned* progArr = isS ? sp : np;
        unsigned* myprog = progArr + a * 32;
        unsigned* lprog = progArr + (leftOK ? (a - 1) : a) * 32;
        unsigned* rprog = progArr + (rightOK ? (a + 1) : a) * 32;

        // one-time: copy pack to LDS (112 KB), zero state
        const unsigned long long* pkG = (const unsigned long long*)(wsu + (isS ? OFF_SPK : OFF_NPK));
        for (int i = tid; i < 14336; i += TB)
            ((unsigned long long*)sm.ns.pk)[i] = pkG[i];
        for (int i = tid; i < 2448; i += TB) ((unsigned*)sm.ns.hst)[i] = 0u;
        for (int i = tid; i < 640; i += TB) ((unsigned*)sm.ns.xa)[i] = 0u;
        float4v creg = (float4v){0.f, 0.f, 0.f, 0.f};
        __syncthreads();

        for (int e = 0; e < NSTEPS; ++e) {
            const int pin = (e + 1) & 1, pout = e & 1;
            // stage x(e)
            if (tid < 32) {
                const float* xp = input + ((size_t)(rg * T_ + e) * S_ + (s0 + tid)) * 4;
                unsigned* row = (unsigned*)sm.ns.xa + tid * 20;
                row[0] = pack2(xp[0], xp[1]);
                row[1] = pack2(xp[2], 1.f);
                row[2] = pack2(xp[3], 1.f);
            }
            // waits: neighbor halos published (prog >= e); d consumed hn(e-2)
            if (e > 0) {
                if (tid == 0 && leftOK)
                    while (ld_dev_u32(lprog) < (unsigned)e) __builtin_amdgcn_s_sleep(2);
                if (tid == 64 && rightOK)
                    while (ld_dev_u32(rprog) < (unsigned)e) __builtin_amdgcn_s_sleep(2);
                if (tid == 128 && e >= 2)
                    while (ld_dev_u32(dc + rg * 32) < (unsigned)(8 * (e - 1))) __builtin_amdgcn_s_sleep(2);
            }
            __syncthreads();
            // halo rows from L3 (parity pin): row0 = r0-1, row33 = r0+32
            if (tid < 64) {
                int side = tid >> 5, p = tid & 31;
                int grow = side ? (r0 + 32) : (r0 - 1);
                bool valid = side ? rightOK : leftOK;
                unsigned v = valid ? ld_dev_u32(hU + (size_t)pin * 65536 + (size_t)grow * 32 + p) : 0u;
                *((unsigned*)&sm.ns.hst[pin][side ? 33 : 0][0] + p) = v;
            }
            __syncthreads();

            // MFMA: wave w -> rowtile rt = w>>2 (16 rows), coltile cg = w&3 (16 cols)
            {
                const int rt = wave >> 2, cg = wave & 3;
                const _Float16* hb = &sm.ns.hst[pin][0][0];
                const int ri = rt * 16 + l15;
                half8 ah0 = *(const half8*)(hb + (ri + 1) * 72 + quad * 8);
                half8 ah1 = *(const half8*)(hb + (ri + 1) * 72 + 32 + quad * 8);
                half8 aa0 = *(const half8*)(hb + (ri + 2) * 72 + quad * 8);
                half8 aa1 = *(const half8*)(hb + (ri + 2) * 72 + 32 + quad * 8);
                half8 ab0 = *(const half8*)(hb + (ri) * 72 + quad * 8);
                half8 ab1 = *(const half8*)(hb + (ri) * 72 + 32 + quad * 8);
                half8 ax  = *(const half8*)(&sm.ns.xa[0][0] + ri * 40 + quad * 8);
                float4v acc[4];
#pragma unroll
                for (int g = 0; g < 4; ++g) acc[g] = (float4v){0.f, 0.f, 0.f, 0.f};
#pragma unroll
                for (int g = 0; g < 4; ++g) {
                    const _Float16* base = sm.ns.pk + (size_t)(4 * g + cg) * 7 * 512 + lane * 8;
                    acc[g] = __builtin_amdgcn_mfma_f32_16x16x32_f16(ah0, *(const half8*)(base),        acc[g], 0, 0, 0);
                    acc[g] = __builtin_amdgcn_mfma_f32_16x16x32_f16(ah1, *(const half8*)(base + 512),  acc[g], 0, 0, 0);
                    acc[g] = __builtin_amdgcn_mfma_f32_16x16x32_f16(aa0, *(const half8*)(base + 1024), acc[g], 0, 0, 0);
                    acc[g] = __builtin_amdgcn_mfma_f32_16x16x32_f16(aa1, *(const half8*)(base + 1536), acc[g], 0, 0, 0);
                    acc[g] = __builtin_amdgcn_mfma_f32_16x16x32_f16(ab0, *(const half8*)(base + 2048), acc[g], 0, 0, 0);
                    acc[g] = __builtin_amdgcn_mfma_f32_16x16x32_f16(ab1, *(const half8*)(base + 2560), acc[g], 0, 0, 0);
                    acc[g] = __builtin_amdgcn_mfma_f32_16x16x32_f16(ax,  *(const half8*)(base + 3072), acc[g], 0, 0, 0);
                }
                float4v cold = creg, cnew;
                _Float16* hLp = &sm.ns.hst[pout][0][0];
                const int kcol = cg * 16 + l15;
#pragma unroll
                for (int r = 0; r < 4; ++r) {
                    float c2 = sigm(acc[1][r]) * cold[r] + sigm(acc[0][r]) * tanh_(acc[2][r]);
                    float h2 = sigm(acc[3][r]) * tanh_(c2);
                    cnew[r] = c2;
                    int row = rt * 16 + quad * 4 + r;
                    hLp[(row + 1) * 72 + kcol] = (_Float16)h2;
                    st_dev_f16(hH + (size_t)pout * 131072 + (size_t)(r0 + row) * 64 + kcol, (_Float16)h2);
                }
                creg = cnew;
            }
            __syncthreads();   // drains all device stores before signaling
            if (tid == 0) at_add_u32(nsc + rg * 32, 1u);
            if (tid == 32) st_dev_u32(myprog, (unsigned)(e + 1));
        }
    } else {
        // ================= d role =================
        const int idx = blk - 128;
        const int rg = idx >> 3;                // batch (128 rows, no halo deps)
        const int c = idx & 7;                  // 16 h-cols slice
        const int r0 = rg * 128;

        // one-time: copy weight slice (64 KB) to LDS; zero hd edge rows
        const unsigned long long* pdG = (const unsigned long long*)(wsu + OFF_DPK);
        for (int i = tid; i < 8192; i += TB) {
            int tile = i >> 7, j = i & 127;
            int g = tile >> 4, tt = tile & 15;
            ((unsigned long long*)sm.d.wd)[(g * 16 + tt) * 128 + j] =
                pdG[(size_t)((g * 8 + c) * 16 + tt) * 128 + j];
        }
        for (int i = tid; i < 136; i += TB) { sm.d.hd[0][i] = (_Float16)0; sm.d.hd[129][i] = (_Float16)0; }
        const int hcol = c * 16 + l15;
        const float won = onW[hcol], wos = osW[hcol];
        float bg[4];
#pragma unroll
        for (int g = 0; g < 4; ++g) bg[g] = db[g * 128 + hcol];
        float4v creg = (float4v){0.f, 0.f, 0.f, 0.f};
        __syncthreads();

        for (int e = 1; e <= NSTEPS; ++e) {
            const int t = e - 1;
            const int pdec = t & 1;             // hn/hs(t) parity
            const int phdin = e & 1;            // hd(t-1) parity
            const int phdout = t & 1;           // hd(t) parity
            // wait siblings done epoch e-1 (hd(t-1) published, hd(t-3) parity free)
            if (tid == 0 && e >= 2)
                while (ld_dev_u32(dc + rg * 32) < (unsigned)(8 * (e - 1))) __builtin_amdgcn_s_sleep(2);
            __syncthreads();
            // stage hd(t-1): rows 1..128 (edges stay zero)
            {
                const unsigned long long* src = (const unsigned long long*)(hdU + (size_t)phdin * 131072);
                for (int i = tid; i < 4096; i += TB) {
                    int row = i >> 5, j = i & 31;
                    unsigned long long v = ld_dev_u64(src + (size_t)(r0 + row) * 32 + j);
                    *((unsigned long long*)&sm.d.hd[row + 1][0] + j) = v;
                }
            }
            // wait n/s done epoch t (dec inputs published)
            if (tid == 0)
                while (ld_dev_u32(nsc + rg * 32) < (unsigned)(8 * e)) __builtin_amdgcn_s_sleep(2);
            __syncthreads();
            // stage dec = [hn(t) | hs(t)]
            for (int i = tid; i < 4096; i += TB) {
                int half = i >> 11, j2 = i & 2047;
                int row = j2 >> 4, j = j2 & 15;
                const unsigned long long* src =
                    (const unsigned long long*)((half ? hsU : hnU) + (size_t)pdec * 65536);
                unsigned long long v = ld_dev_u64(src + (size_t)(r0 + row) * 16 + j);
                *((unsigned long long*)&sm.d.dec[row][half * 64] + j) = v;
            }
            __syncthreads();

            // MFMA: wave w -> rows w*16..w*16+15, all 4 gates x 16 cols of slice
            {
                const int ri = wave * 16 + l15;
                half8 fr[16];
#pragma unroll
                for (int kt = 0; kt < 4; ++kt) {
                    fr[kt]      = *(const half8*)(&sm.d.dec[ri][0] + kt * 32 + quad * 8);
                    fr[4 + kt]  = *(const half8*)(&sm.d.hd[ri + 1][0] + kt * 32 + quad * 8);
                    fr[8 + kt]  = *(const half8*)(&sm.d.hd[ri + 2][0] + kt * 32 + quad * 8);
                    fr[12 + kt] = *(const half8*)(&sm.d.hd[ri][0] + kt * 32 + quad * 8);
                }
                float4v acc[4];
#pragma unroll
                for (int g = 0; g < 4; ++g) acc[g] = (float4v){0.f, 0.f, 0.f, 0.f};
#pragma unroll
                for (int g = 0; g < 4; ++g) {
                    const _Float16* bw = sm.d.wd + (size_t)(g * 16) * 512 + lane * 8;
#pragma unroll
                    for (int kt = 0; kt < 16; ++kt)
                        acc[g] = __builtin_amdgcn_mfma_f32_16x16x32_f16(fr[kt], *(const half8*)(bw + kt * 512), acc[g], 0, 0, 0);
                }
                float4v cold = creg, cnew;
#pragma unroll
                for (int r = 0; r < 4; ++r) {
                    float c2 = sigm(acc[1][r] + bg[1]) * cold[r] + sigm(acc[0][r] + bg[0]) * tanh_(acc[2][r] + bg[2]);
                    float h2 = sigm(acc[3][r] + bg[3]) * tanh_(c2);
                    cnew[r] = c2;
                    int row = wave * 16 + quad * 4 + r;
                    st_dev_f16(hdH + (size_t)phdout * 262144 + (size_t)(r0 + row) * 128 + hcol, (_Float16)h2);
                    float pon = h2 * won, pos = h2 * wos;
#pragma unroll
                    for (int off = 8; off; off >>= 1) {
                        pon += __shfl_down(pon, off, 16);
                        pos += __shfl_down(pos, off, 16);
                    }
                    if (l15 == 0) {
                        float* o = outs + ((size_t)t * ROWS + (r0 + row)) * 2;
                        at_add_f32(o, pon);
                        at_add_f32(o + 1, pos);
                    }
                }
                creg = cnew;
            }
            __syncthreads();   // drains publishes + atomics before signaling
            if (tid == 0) at_add_u32(dc + rg * 32, 1u);
        }
    }
}

// Assemble data outputs for t in [20,126]; head biases added here.
__global__ __launch_bounds__(256) void assemble_kernel(
    const float* __restrict__ input, const float* __restrict__ ws, float* __restrict__ out,
    const float* __restrict__ onb, const float* __restrict__ osb)
{
    const float* outs = ws + OFF_OUTS;
    int idx = blockIdx.x * 256 + threadIdx.x;  // (b, tt, s)
    if (idx >= B_ * TOUT * S_) return;
    float b_on = onb[0], b_os = osb[0];
    int s = idx & 127;
    int tmp = idx >> 7;
    int tt = tmp % TOUT;
    int b = tmp / TOUT;
    int t = tt + TPRED;
    int row = b * S_ + s;
    float o0 = outs[((size_t)t * ROWS + row) * 2 + 0] + b_on;
    float o1 = outs[((size_t)t * ROWS + row) * 2 + 1] + b_os;
    float inflow = (s == 0) ? input[(((size_t)b * T_ + (t + 1)) * S_ + 0) * 4 + 1]
                            : (outs[((size_t)t * ROWS + row - 1) * 2 + 0] + b_on);
    float numc = input[(((size_t)b * T_ + t) * S_ + s) * 4 + 2] + inflow - o0;
    float spd = (s == 0) ? input[(((size_t)b * T_ + (t + 1)) * S_ + 0) * 4 + 3] : o1;
    float4 v = make_float4(o0, inflow, numc, spd);
    reinterpret_cast<float4*>(out)[idx] = v;
}

extern "C" void kernel_launch(void* const* d_in, const int* in_sizes, int n_in,
                              void* d_out, int out_size, void* d_ws, size_t ws_size,
                              hipStream_t stream) {
    const float* input = (const float*)d_in[0];
    const float* nWx = (const float*)d_in[1];
    const float* nWh = (const float*)d_in[2];
    const float* nWa = (const float*)d_in[3];
    const float* nWb = (const float*)d_in[4];
    const float* nb  = (const float*)d_in[5];
    const float* sWx = (const float*)d_in[6];
    const float* sWh = (const float*)d_in[7];
    const float* sWa = (const float*)d_in[8];
    const float* sWb = (const float*)d_in[9];
    const float* sb  = (const float*)d_in[10];
    const float* dWx = (const float*)d_in[11];
    const float* dWh = (const float*)d_in[12];
    const float* dWa = (const float*)d_in[13];
    const float* dWb = (const float*)d_in[14];
    const float* db  = (const float*)d_in[15];
    const float* onW = (const float*)d_in[16];
    const float* onb = (const float*)d_in[17];
    const float* osW = (const float*)d_in[18];
    const float* osb = (const float*)d_in[19];

    float* ws = (float*)d_ws;

    // zero h buffers (both parities), sync counters, and outs accumulator
    hipMemsetAsync(ws, 0, (size_t)ZERO_DW * 4, stream);

    // pack weights into MFMA B-fragment tiles (once per call)
    pack_weights<<<dim3((PACK_DWORDS + 255) / 256), dim3(256), 0, stream>>>(
        nWx, nWh, nWa, nWb, nb, sWx, sWh, sWa, sWb, sb,
        dWx, dWh, dWa, dWb, (unsigned int*)ws);

    // cooperative launch (co-residency guarantee); sync via counters inside
    void* kargs[] = {
        (void*)&input, (void*)&db, (void*)&onW, (void*)&onb,
        (void*)&osW, (void*)&osb, (void*)&ws
    };
    hipLaunchCooperativeKernel((void*)pipe_persist, dim3(NBLK), dim3(TB),
                               kargs, 0, stream);

    int nout = B_ * TOUT * S_;
    assemble_kernel<<<dim3((nout + 255) / 256), dim3(256), 0, stream>>>(
        input, ws, (float*)d_out, onb, osb);
}